// Round 1
// baseline (1622.199 us; speedup 1.0000x reference)
//
#include <hip/hip_runtime.h>

typedef unsigned short ushort_t;
typedef __attribute__((ext_vector_type(4)))  float f32x4;
typedef __attribute__((ext_vector_type(16))) float f32x16;
typedef __attribute__((ext_vector_type(8)))  short s16x8;
typedef __attribute__((ext_vector_type(4)))  short s16x4;

#define AS1C(p) ((const __attribute__((address_space(1))) void*)(p))
#define AS3(p)  ((__attribute__((address_space(3))) void*)(p))

// dims
#define VV 32000
#define HH 1024
#define BB 32
#define SS 64

__device__ __forceinline__ ushort_t f2bf(float f){
  unsigned u = __builtin_bit_cast(unsigned, f);
  unsigned r = u + 0x7fffu + ((u >> 16) & 1u);
  return (ushort_t)(r >> 16);
}

// ---------------- fp32 -> bf16 convert (n multiple of 4) ----------------
__global__ __launch_bounds__(256) void k_f32_to_bf16(const float* __restrict__ src,
                                                     ushort_t* __restrict__ dst, int n4){
  int i = blockIdx.x * 256 + threadIdx.x;
  if (i >= n4) return;
  f32x4 v = *(const f32x4*)(src + (size_t)i * 4);
  s16x4 o;
  #pragma unroll
  for (int j = 0; j < 4; j++) o[j] = (short)f2bf(v[j]);
  *(s16x4*)(dst + (size_t)i * 4) = o;
}

// ---------------- token gather + relu -> bf16 x[r=s*32+b][k] ----------------
__global__ __launch_bounds__(256) void k_embed(const float* __restrict__ emb,
                                               const int* __restrict__ tgt,
                                               const int* __restrict__ bosp,
                                               ushort_t* __restrict__ xb){
  int r = blockIdx.x;            // 0..2047
  int s = r >> 5, b = r & 31;
  int tok = (s == 0) ? bosp[0] : tgt[b * SS + (s - 1)];
  const float* src = emb + (size_t)tok * HH;
  ushort_t* dst = xb + (size_t)r * HH;
  int k4 = threadIdx.x * 4;      // 256*4 = 1024
  f32x4 v = *(const f32x4*)(src + k4);
  s16x4 o;
  #pragma unroll
  for (int j = 0; j < 4; j++){ float x = v[j]; x = x > 0.f ? x : 0.f; o[j] = (short)f2bf(x); }
  *(s16x4*)(dst + k4) = o;
}

// ---------------- m97-style bf16 BT-GEMM: C[M,N] = A[M,K] @ B[N,K]^T + bias ----------------
// permute: out row r=(s*32+b) written to row b*64+s (for logits [B,S,V] layout)
__global__ __launch_bounds__(256) void k_gemm_bt(const ushort_t* __restrict__ A,
                                                 const ushort_t* __restrict__ Bw,
                                                 const float* __restrict__ bias,
                                                 float* __restrict__ C,
                                                 int M, int N, int K, int permute){
  __shared__ ushort_t sA[128 * 32];   // 8KB
  __shared__ ushort_t sB[128 * 32];   // 8KB
  int m0 = blockIdx.x * 128;
  int n0 = blockIdx.y * 128;
  int tid = threadIdx.x;
  int lane = tid & 63, wave = tid >> 6;
  int wm = (wave >> 1) * 64, wn = (wave & 1) * 64;
  int l16 = lane & 15, quad = lane >> 4;
  f32x4 acc[4][4] = {};
  for (int k0 = 0; k0 < K; k0 += 32){
    #pragma unroll
    for (int i = 0; i < 2; i++){
      int id = tid + i * 256;          // 512 chunks of 16B per 8KB tile
      int row = id >> 2, kc = id & 3;  // 4 chunks per 32-elem row
      __builtin_amdgcn_global_load_lds(AS1C(A + (size_t)(m0 + row) * K + k0 + kc * 8),
                                       AS3(sA + (size_t)id * 8), 16, 0, 0);
      __builtin_amdgcn_global_load_lds(AS1C(Bw + (size_t)(n0 + row) * K + k0 + kc * 8),
                                       AS3(sB + (size_t)id * 8), 16, 0, 0);
    }
    __syncthreads();
    s16x8 af[4], bf[4];
    #pragma unroll
    for (int t = 0; t < 4; t++){
      af[t] = *(const s16x8*)(sA + (wm + t * 16 + l16) * 32 + quad * 8);
      bf[t] = *(const s16x8*)(sB + (wn + t * 16 + l16) * 32 + quad * 8);
    }
    #pragma unroll
    for (int mt = 0; mt < 4; mt++)
      #pragma unroll
      for (int nt = 0; nt < 4; nt++)
        acc[mt][nt] = __builtin_amdgcn_mfma_f32_16x16x32_bf16(af[mt], bf[nt], acc[mt][nt], 0, 0, 0);
    __syncthreads();
  }
  #pragma unroll
  for (int nt = 0; nt < 4; nt++){
    int col = n0 + wn + nt * 16 + l16;
    float bs = bias ? bias[col] : 0.f;
    #pragma unroll
    for (int mt = 0; mt < 4; mt++){
      #pragma unroll
      for (int r = 0; r < 4; r++){
        int row = m0 + wm + mt * 16 + quad * 4 + r;
        int orow = permute ? ((row & 31) * SS + (row >> 5)) : row;
        C[(size_t)orow * N + col] = acc[mt][nt][r] + bs;
      }
    }
  }
}

// ---------------- one GRU step: 32 WGs, j-tile of 32; M=batch=32 via mfma 32x32x16 ----------------
__global__ __launch_bounds__(256) void k_gru_step(const ushort_t* __restrict__ hprev_bf, // [32,1024]
                                                  const float* __restrict__ hprev_f,     // [32,1024]
                                                  const ushort_t* __restrict__ Whh,      // [3072,1024] bf16
                                                  const float* __restrict__ gi_s,        // [32,3072] (this step)
                                                  const float* __restrict__ b_hh,        // [3072]
                                                  ushort_t* __restrict__ hout_bf,        // [32,1024]
                                                  float* __restrict__ hout_f){           // [32,1024]
  int tid = threadIdx.x;
  int lane = tid & 63, wave = tid >> 6;
  int j0 = blockIdx.x * 32;
  int m = lane & 31, q = lane >> 5;
  int kbase = wave * 256;                      // waves split K=1024
  f32x16 acc0 = {}, acc1 = {}, acc2 = {};
  const ushort_t* arow = hprev_bf + (size_t)m * HH + kbase + q * 8;
  const ushort_t* b0 = Whh + (size_t)(0 * HH + j0 + m) * HH + kbase + q * 8;
  const ushort_t* b1 = Whh + (size_t)(1 * HH + j0 + m) * HH + kbase + q * 8;
  const ushort_t* b2 = Whh + (size_t)(2 * HH + j0 + m) * HH + kbase + q * 8;
  #pragma unroll
  for (int kk = 0; kk < 256; kk += 16){
    s16x8 a = *(const s16x8*)(arow + kk);
    acc0 = __builtin_amdgcn_mfma_f32_32x32x16_bf16(a, *(const s16x8*)(b0 + kk), acc0, 0, 0, 0);
    acc1 = __builtin_amdgcn_mfma_f32_32x32x16_bf16(a, *(const s16x8*)(b1 + kk), acc1, 0, 0, 0);
    acc2 = __builtin_amdgcn_mfma_f32_32x32x16_bf16(a, *(const s16x8*)(b2 + kk), acc2, 0, 0, 0);
  }
  __shared__ float red[4][3][1024];            // 48KB: per-wave partial C tiles
  #pragma unroll
  for (int r = 0; r < 16; r++){
    int row = (r & 3) + 8 * (r >> 2) + 4 * q;  // verified 32x32 C/D mapping
    red[wave][0][row * 32 + m] = acc0[r];
    red[wave][1][row * 32 + m] = acc1[r];
    red[wave][2][row * 32 + m] = acc2[r];
  }
  __syncthreads();
  #pragma unroll
  for (int i = 0; i < 4; i++){
    int e = tid + i * 256;                     // 1024 (b,j) elements
    int b = e >> 5, j = e & 31;
    int jj = j0 + j;
    float hr = red[0][0][e] + red[1][0][e] + red[2][0][e] + red[3][0][e] + b_hh[jj];
    float hz = red[0][1][e] + red[1][1][e] + red[2][1][e] + red[3][1][e] + b_hh[HH + jj];
    float hn = red[0][2][e] + red[1][2][e] + red[2][2][e] + red[3][2][e] + b_hh[2 * HH + jj];
    const float* gib = gi_s + (size_t)b * (3 * HH);
    float r_ = 1.f / (1.f + __expf(-(gib[jj] + hr)));
    float z_ = 1.f / (1.f + __expf(-(gib[HH + jj] + hz)));
    float n_ = tanhf(gib[2 * HH + jj] + r_ * hn);
    float hp = hprev_f[b * HH + jj];
    float hv = (1.f - z_) * n_ + z_ * hp;
    hout_f[b * HH + jj] = hv;
    hout_bf[b * HH + jj] = f2bf(hv);
  }
}

// ---------------- in-place log_softmax over rows of 32000 ----------------
__global__ __launch_bounds__(256) void k_logsoftmax(float* __restrict__ out){
  float* p = out + (size_t)blockIdx.x * VV;
  int tid = threadIdx.x;
  float m = -3.0e38f, l = 0.f;
  for (int i = tid; i < VV; i += 256){
    float x = p[i];
    float mn = fmaxf(m, x);
    l = l * __expf(m - mn) + __expf(x - mn);
    m = mn;
  }
  #pragma unroll
  for (int off = 32; off; off >>= 1){
    float mo = __shfl_down(m, off);
    float lo = __shfl_down(l, off);
    float mn = fmaxf(m, mo);
    l = l * __expf(m - mn) + lo * __expf(mo - mn);
    m = mn;
  }
  __shared__ float sm[4], sl[4];
  int w = tid >> 6;
  if ((tid & 63) == 0){ sm[w] = m; sl[w] = l; }
  __syncthreads();
  float M = fmaxf(fmaxf(sm[0], sm[1]), fmaxf(sm[2], sm[3]));
  float L = sl[0] * __expf(sm[0] - M) + sl[1] * __expf(sm[1] - M)
          + sl[2] * __expf(sm[2] - M) + sl[3] * __expf(sm[3] - M);
  float off = M + __logf(L);
  for (int i = tid; i < VV; i += 256) p[i] -= off;   // second read is L2/L3-hot
}

__global__ __launch_bounds__(256) void k_copy(const float* __restrict__ src,
                                              float* __restrict__ dst, int n){
  int i = blockIdx.x * 256 + threadIdx.x;
  if (i < n) dst[i] = src[i];
}

extern "C" void kernel_launch(void* const* d_in, const int* in_sizes, int n_in,
                              void* d_out, int out_size, void* d_ws, size_t ws_size,
                              hipStream_t stream){
  const float* enc_hid = (const float*)d_in[1];   // [1,B,H] == h0
  const int*   bosp    = (const int*)d_in[2];
  const int*   tgt     = (const int*)d_in[3];     // [B,S]
  const float* emb     = (const float*)d_in[4];   // [V,H]
  const float* W_ih    = (const float*)d_in[5];   // [3H,H]
  const float* W_hh    = (const float*)d_in[6];   // [3H,H]
  const float* b_ih    = (const float*)d_in[7];
  const float* b_hh    = (const float*)d_in[8];
  const float* W_out   = (const float*)d_in[9];   // [V,H]
  const float* b_out   = (const float*)d_in[10];
  float* out = (float*)d_out;

  // workspace layout (~115 MB)
  const size_t NWOUT = (size_t)VV * HH;       // 32,768,000
  const size_t NW3H  = (size_t)3 * HH * HH;   // 3,145,728
  const size_t NX    = (size_t)SS * BB * HH;  // 2,097,152
  const size_t NH0   = (size_t)BB * HH;       // 32,768
  const size_t NGI   = (size_t)SS * BB * 3 * HH; // 6,291,456
  ushort_t* wout_bf = (ushort_t*)d_ws;
  ushort_t* wih_bf  = wout_bf + NWOUT;
  ushort_t* whh_bf  = wih_bf + NW3H;
  ushort_t* x_bf    = whh_bf + NW3H;
  ushort_t* h0_bf   = x_bf + NX;
  ushort_t* hs_bf   = h0_bf + NH0;
  float*    gi      = (float*)(hs_bf + NX);   // offset is 16B-aligned
  float*    hs_f    = gi + NGI;

  // 1) weight / h0 converts to bf16
  k_f32_to_bf16<<<(int)((NWOUT/4 + 255)/256), 256, 0, stream>>>(W_out, wout_bf, (int)(NWOUT/4));
  k_f32_to_bf16<<<(int)((NW3H/4  + 255)/256), 256, 0, stream>>>(W_ih,  wih_bf,  (int)(NW3H/4));
  k_f32_to_bf16<<<(int)((NW3H/4  + 255)/256), 256, 0, stream>>>(W_hh,  whh_bf,  (int)(NW3H/4));
  k_f32_to_bf16<<<(int)((NH0/4   + 255)/256), 256, 0, stream>>>(enc_hid, h0_bf, (int)(NH0/4));

  // 2) x = relu(emb[tok]) in bf16, rows r = s*32+b
  k_embed<<<SS*BB, 256, 0, stream>>>(emb, tgt, bosp, x_bf);

  // 3) gi = x @ W_ih^T + b_ih   (M=2048, N=3072, K=1024)
  k_gemm_bt<<<dim3(16, 24), 256, 0, stream>>>(x_bf, wih_bf, b_ih, gi, 2048, 3072, 1024, 0);

  // 4) recurrence: 64 sequential step launches
  for (int s = 0; s < SS; s++){
    const ushort_t* hp_bf = s ? hs_bf + (size_t)(s - 1) * NH0 : h0_bf;
    const float*    hp_f  = s ? hs_f + (size_t)(s - 1) * NH0 : enc_hid;
    k_gru_step<<<32, 256, 0, stream>>>(hp_bf, hp_f, whh_bf,
                                       gi + (size_t)s * BB * 3 * HH, b_hh,
                                       hs_bf + (size_t)s * NH0,
                                       hs_f + (size_t)s * NH0);
  }

  // 5) hT -> d_out tail
  k_copy<<<(int)((NH0 + 255)/256), 256, 0, stream>>>(hs_f + (size_t)63 * NH0,
                                                     out + (size_t)BB * SS * VV, (int)NH0);

  // 6) logits = hs @ W_out^T + b_out, written permuted into [B,S,V] region of d_out
  k_gemm_bt<<<dim3(16, 250), 256, 0, stream>>>(hs_bf, wout_bf, b_out, out, 2048, VV, 1024, 1);

  // 7) in-place log_softmax per (b,s) row
  k_logsoftmax<<<SS*BB, 256, 0, stream>>>(out);
}

// Round 2
// 1410.834 us; speedup vs baseline: 1.1498x; 1.1498x over previous
//
#include <hip/hip_runtime.h>

typedef unsigned short ushort_t;
typedef __attribute__((ext_vector_type(4)))  float f32x4;
typedef __attribute__((ext_vector_type(8)))  short s16x8;
typedef __attribute__((ext_vector_type(4)))  short s16x4;

#define AS1C(p) ((const __attribute__((address_space(1))) void*)(p))
#define AS3(p)  ((__attribute__((address_space(3))) void*)(p))

// dims
#define VV 32000
#define HH 1024
#define BB 32
#define SS 64
#define GRU_WGS 64

__device__ __forceinline__ ushort_t f2bf(float f){
  unsigned u = __builtin_bit_cast(unsigned, f);
  unsigned r = u + 0x7fffu + ((u >> 16) & 1u);
  return (ushort_t)(r >> 16);
}
__device__ __forceinline__ float bf2f(ushort_t u){
  unsigned x = ((unsigned)u) << 16;
  return __builtin_bit_cast(float, x);
}

// ---------------- fp32 -> bf16 convert (n multiple of 4) ----------------
__global__ __launch_bounds__(256) void k_f32_to_bf16(const float* __restrict__ src,
                                                     ushort_t* __restrict__ dst, int n4){
  int i = blockIdx.x * 256 + threadIdx.x;
  if (i >= n4) return;
  f32x4 v = *(const f32x4*)(src + (size_t)i * 4);
  s16x4 o;
  #pragma unroll
  for (int j = 0; j < 4; j++) o[j] = (short)f2bf(v[j]);
  *(s16x4*)(dst + (size_t)i * 4) = o;
}

// ---------------- token gather + relu -> bf16 x[r=s*32+b][k] ----------------
__global__ __launch_bounds__(256) void k_embed(const float* __restrict__ emb,
                                               const int* __restrict__ tgt,
                                               const int* __restrict__ bosp,
                                               ushort_t* __restrict__ xb){
  int r = blockIdx.x;            // 0..2047
  int s = r >> 5, b = r & 31;
  int tok = (s == 0) ? bosp[0] : tgt[b * SS + (s - 1)];
  const float* src = emb + (size_t)tok * HH;
  ushort_t* dst = xb + (size_t)r * HH;
  int k4 = threadIdx.x * 4;      // 256*4 = 1024
  f32x4 v = *(const f32x4*)(src + k4);
  s16x4 o;
  #pragma unroll
  for (int j = 0; j < 4; j++){ float x = v[j]; x = x > 0.f ? x : 0.f; o[j] = (short)f2bf(x); }
  *(s16x4*)(dst + k4) = o;
}

// ---------------- m97-style bf16 BT-GEMM: C[M,N] = A[M,K] @ B[N,K]^T + bias ----------------
// permute: out row r=(s*32+b) written to row b*64+s (for logits [B,S,V] layout)
template<bool BF16OUT>
__global__ __launch_bounds__(256) void k_gemm_bt(const ushort_t* __restrict__ A,
                                                 const ushort_t* __restrict__ Bw,
                                                 const float* __restrict__ bias,
                                                 void* __restrict__ Cv,
                                                 int M, int N, int K, int permute){
  __shared__ ushort_t sA[128 * 32];   // 8KB
  __shared__ ushort_t sB[128 * 32];   // 8KB
  int m0 = blockIdx.x * 128;
  int n0 = blockIdx.y * 128;
  int tid = threadIdx.x;
  int lane = tid & 63, wave = tid >> 6;
  int wm = (wave >> 1) * 64, wn = (wave & 1) * 64;
  int l16 = lane & 15, quad = lane >> 4;
  f32x4 acc[4][4] = {};
  for (int k0 = 0; k0 < K; k0 += 32){
    #pragma unroll
    for (int i = 0; i < 2; i++){
      int id = tid + i * 256;          // 512 chunks of 16B per 8KB tile
      int row = id >> 2, kc = id & 3;  // 4 chunks per 32-elem row
      __builtin_amdgcn_global_load_lds(AS1C(A + (size_t)(m0 + row) * K + k0 + kc * 8),
                                       AS3(sA + (size_t)id * 8), 16, 0, 0);
      __builtin_amdgcn_global_load_lds(AS1C(Bw + (size_t)(n0 + row) * K + k0 + kc * 8),
                                       AS3(sB + (size_t)id * 8), 16, 0, 0);
    }
    __syncthreads();
    s16x8 af[4], bf[4];
    #pragma unroll
    for (int t = 0; t < 4; t++){
      af[t] = *(const s16x8*)(sA + (wm + t * 16 + l16) * 32 + quad * 8);
      bf[t] = *(const s16x8*)(sB + (wn + t * 16 + l16) * 32 + quad * 8);
    }
    #pragma unroll
    for (int mt = 0; mt < 4; mt++)
      #pragma unroll
      for (int nt = 0; nt < 4; nt++)
        acc[mt][nt] = __builtin_amdgcn_mfma_f32_16x16x32_bf16(af[mt], bf[nt], acc[mt][nt], 0, 0, 0);
    __syncthreads();
  }
  #pragma unroll
  for (int nt = 0; nt < 4; nt++){
    int col = n0 + wn + nt * 16 + l16;
    float bs = bias ? bias[col] : 0.f;
    #pragma unroll
    for (int mt = 0; mt < 4; mt++){
      #pragma unroll
      for (int r = 0; r < 4; r++){
        int row = m0 + wm + mt * 16 + quad * 4 + r;
        int orow = permute ? ((row & 31) * SS + (row >> 5)) : row;
        float v = acc[mt][nt][r] + bs;
        if (BF16OUT) ((ushort_t*)Cv)[(size_t)orow * N + col] = f2bf(v);
        else         ((float*)Cv)[(size_t)orow * N + col] = v;
      }
    }
  }
}

// ---------------- persistent GRU: 64 WGs, one launch, grid barrier per step ----------------
// WG wg owns j-columns [wg*16, wg*16+16) for all 3 gates. Whh slice staged in LDS once.
__global__ __launch_bounds__(256) void k_gru_persist(
    const ushort_t* __restrict__ h0_bf, const float* __restrict__ h0_f,
    const ushort_t* __restrict__ Whh,   // [3*HH, HH] bf16
    const ushort_t* __restrict__ gi,    // [SS][BB][3*HH] bf16
    const float* __restrict__ b_hh,
    ushort_t* __restrict__ hs_bf,       // [SS][BB][HH]
    float* __restrict__ hT,             // [BB][HH] fp32 (output tail)
    unsigned* __restrict__ bar){
  __shared__ ushort_t sW[3][16][1032];  // 96.75KB, +8 pad breaks 2KB-stride bank aliasing
  __shared__ float red[4][3][32][17];   // 26.1KB, +1 pad
  int tid = threadIdx.x;
  int wg = blockIdx.x;
  int j0 = wg * 16;
  int lane = tid & 63, wave = tid >> 6;
  int l16 = lane & 15, quad = lane >> 4;

  // stage Whh slice: 48 rows x 1024 bf16, fully coalesced (128 x 16B chunks per row)
  for (int idx = tid; idx < 48 * 128; idx += 256){
    int row = idx >> 7, c = idx & 127;
    *(s16x8*)&sW[row >> 4][row & 15][c * 8] =
        *(const s16x8*)(Whh + (size_t)((row >> 4) * HH + j0 + (row & 15)) * HH + c * 8);
  }
  // per-thread h (fp32 carried exactly) + bias registers: elems e=tid, tid+256 -> (b=e>>4, jj=e&15)
  float hreg[2]; float bh[2][3];
  #pragma unroll
  for (int i = 0; i < 2; i++){
    int e = tid + i * 256, b = e >> 4, jj = e & 15;
    hreg[i] = h0_f[b * HH + j0 + jj];
    bh[i][0] = b_hh[j0 + jj];
    bh[i][1] = b_hh[HH + j0 + jj];
    bh[i][2] = b_hh[2 * HH + j0 + jj];
  }
  __syncthreads();

  int kb = wave * 256;                  // waves split K=1024
  for (int s = 0; s < SS; s++){
    const ushort_t* hp = s ? (hs_bf + (size_t)(s - 1) * BB * HH) : h0_bf;
    f32x4 acc[3][2] = {};
    #pragma unroll
    for (int kk = 0; kk < 8; kk++){
      int ko = kb + kk * 32 + quad * 8;
      s16x8 a0 = *(const s16x8*)(hp + (size_t)l16 * HH + ko);
      s16x8 a1 = *(const s16x8*)(hp + (size_t)(16 + l16) * HH + ko);
      #pragma unroll
      for (int g = 0; g < 3; g++){
        s16x8 bfr = *(const s16x8*)&sW[g][l16][ko];
        acc[g][0] = __builtin_amdgcn_mfma_f32_16x16x32_bf16(a0, bfr, acc[g][0], 0, 0, 0);
        acc[g][1] = __builtin_amdgcn_mfma_f32_16x16x32_bf16(a1, bfr, acc[g][1], 0, 0, 0);
      }
    }
    // K-reduce across waves via LDS; C/D map: col=l16 (jj), row=quad*4+r (batch within half)
    #pragma unroll
    for (int g = 0; g < 3; g++)
      #pragma unroll
      for (int mh = 0; mh < 2; mh++)
        #pragma unroll
        for (int r = 0; r < 4; r++)
          red[wave][g][mh * 16 + quad * 4 + r][l16] = acc[g][mh][r];
    __syncthreads();
    ushort_t* ho = hs_bf + (size_t)s * BB * HH;
    #pragma unroll
    for (int i = 0; i < 2; i++){
      int e = tid + i * 256, b = e >> 4, jj = e & 15;
      float hr = red[0][0][b][jj] + red[1][0][b][jj] + red[2][0][b][jj] + red[3][0][b][jj] + bh[i][0];
      float hz = red[0][1][b][jj] + red[1][1][b][jj] + red[2][1][b][jj] + red[3][1][b][jj] + bh[i][1];
      float hn = red[0][2][b][jj] + red[1][2][b][jj] + red[2][2][b][jj] + red[3][2][b][jj] + bh[i][2];
      const ushort_t* gib = gi + (size_t)s * BB * 3 * HH + (size_t)b * 3 * HH;
      float r_ = 1.f / (1.f + __expf(-(bf2f(gib[j0 + jj]) + hr)));
      float z_ = 1.f / (1.f + __expf(-(bf2f(gib[HH + j0 + jj]) + hz)));
      float n_ = tanhf(bf2f(gib[2 * HH + j0 + jj]) + r_ * hn);
      float hv = (1.f - z_) * n_ + z_ * hreg[i];
      hreg[i] = hv;
      ho[b * HH + j0 + jj] = f2bf(hv);
    }
    // device-wide barrier (64 co-resident WGs): release h writes, then arrive+spin
    __threadfence();
    __syncthreads();
    if (tid == 0){
      __hip_atomic_fetch_add(bar, 1u, __ATOMIC_ACQ_REL, __HIP_MEMORY_SCOPE_AGENT);
      unsigned tgt = (unsigned)(s + 1) * GRU_WGS;
      while (__hip_atomic_load(bar, __ATOMIC_ACQUIRE, __HIP_MEMORY_SCOPE_AGENT) < tgt)
        __builtin_amdgcn_s_sleep(4);
    }
    __syncthreads();
  }
  #pragma unroll
  for (int i = 0; i < 2; i++){
    int e = tid + i * 256, b = e >> 4, jj = e & 15;
    hT[b * HH + j0 + jj] = hreg[i];
  }
}

// ---------------- log_softmax from bf16 logits: LDS row cache, single HBM read ----------------
__global__ __launch_bounds__(256) void k_lsm_bf(const ushort_t* __restrict__ lg,
                                                float* __restrict__ out){
  __shared__ ushort_t srow[VV];          // 64KB
  __shared__ float sm[4], sl[4];
  const ushort_t* p = lg + (size_t)blockIdx.x * VV;
  float* q = out + (size_t)blockIdx.x * VV;
  int tid = threadIdx.x;
  float m = -3.0e38f, l = 0.f;
  for (int c = tid; c < VV / 8; c += 256){
    s16x8 v = *(const s16x8*)(p + c * 8);
    *(s16x8*)(srow + c * 8) = v;
    #pragma unroll
    for (int j = 0; j < 8; j++){
      float x = bf2f((ushort_t)v[j]);
      float mn = fmaxf(m, x);
      l = l * __expf(m - mn) + __expf(x - mn);
      m = mn;
    }
  }
  #pragma unroll
  for (int off = 32; off; off >>= 1){
    float mo = __shfl_down(m, off);
    float lo = __shfl_down(l, off);
    float mn = fmaxf(m, mo);
    l = l * __expf(m - mn) + lo * __expf(mo - mn);
    m = mn;
  }
  int w = tid >> 6;
  if ((tid & 63) == 0){ sm[w] = m; sl[w] = l; }
  __syncthreads();
  float M = fmaxf(fmaxf(sm[0], sm[1]), fmaxf(sm[2], sm[3]));
  float L = sl[0] * __expf(sm[0] - M) + sl[1] * __expf(sm[1] - M)
          + sl[2] * __expf(sm[2] - M) + sl[3] * __expf(sm[3] - M);
  float off = M + __logf(L);
  for (int c = tid; c < VV / 8; c += 256){
    s16x8 v = *(const s16x8*)(srow + c * 8);   // same chunks this thread wrote
    f32x4 o0, o1;
    #pragma unroll
    for (int j = 0; j < 4; j++){ o0[j] = bf2f((ushort_t)v[j]) - off; o1[j] = bf2f((ushort_t)v[4 + j]) - off; }
    *(f32x4*)(q + c * 8) = o0;
    *(f32x4*)(q + c * 8 + 4) = o1;
  }
}

// ---------------- fallback: in-place fp32 log_softmax (round-1 proven) ----------------
__global__ __launch_bounds__(256) void k_logsoftmax(float* __restrict__ out){
  float* p = out + (size_t)blockIdx.x * VV;
  int tid = threadIdx.x;
  float m = -3.0e38f, l = 0.f;
  for (int i = tid; i < VV; i += 256){
    float x = p[i];
    float mn = fmaxf(m, x);
    l = l * __expf(m - mn) + __expf(x - mn);
    m = mn;
  }
  #pragma unroll
  for (int off = 32; off; off >>= 1){
    float mo = __shfl_down(m, off);
    float lo = __shfl_down(l, off);
    float mn = fmaxf(m, mo);
    l = l * __expf(m - mn) + lo * __expf(mo - mn);
    m = mn;
  }
  __shared__ float sm[4], sl[4];
  int w = tid >> 6;
  if ((tid & 63) == 0){ sm[w] = m; sl[w] = l; }
  __syncthreads();
  float M = fmaxf(fmaxf(sm[0], sm[1]), fmaxf(sm[2], sm[3]));
  float L = sl[0] * __expf(sm[0] - M) + sl[1] * __expf(sm[1] - M)
          + sl[2] * __expf(sm[2] - M) + sl[3] * __expf(sm[3] - M);
  float off = M + __logf(L);
  for (int i = tid; i < VV; i += 256) p[i] -= off;
}

extern "C" void kernel_launch(void* const* d_in, const int* in_sizes, int n_in,
                              void* d_out, int out_size, void* d_ws, size_t ws_size,
                              hipStream_t stream){
  const float* enc_hid = (const float*)d_in[1];   // [1,B,H] == h0 (fp32)
  const int*   bosp    = (const int*)d_in[2];
  const int*   tgt     = (const int*)d_in[3];     // [B,S]
  const float* emb     = (const float*)d_in[4];   // [V,H]
  const float* W_ih    = (const float*)d_in[5];   // [3H,H]
  const float* W_hh    = (const float*)d_in[6];   // [3H,H]
  const float* b_ih    = (const float*)d_in[7];
  const float* b_hh    = (const float*)d_in[8];
  const float* W_out   = (const float*)d_in[9];   // [V,H]
  const float* b_out   = (const float*)d_in[10];
  float* out = (float*)d_out;

  // workspace layout (bytes, all 16B aligned)
  const size_t NWOUT = (size_t)VV * HH;            // 32,768,000 bf16
  const size_t NW3H  = (size_t)3 * HH * HH;        // 3,145,728 bf16
  const size_t NX    = (size_t)SS * BB * HH;       // 2,097,152 bf16
  const size_t NH0   = (size_t)BB * HH;            // 32,768 bf16
  const size_t NGI   = (size_t)SS * BB * 3 * HH;   // 6,291,456 bf16
  char* wp = (char*)d_ws;
  ushort_t* wout_bf = (ushort_t*)wp;               wp += NWOUT * 2;
  ushort_t* wih_bf  = (ushort_t*)wp;               wp += NW3H * 2;
  ushort_t* whh_bf  = (ushort_t*)wp;               wp += NW3H * 2;
  ushort_t* x_bf    = (ushort_t*)wp;               wp += NX * 2;
  ushort_t* h0_bf   = (ushort_t*)wp;               wp += NH0 * 2;
  ushort_t* hs_bf   = (ushort_t*)wp;               wp += NX * 2;
  ushort_t* gi_bf   = (ushort_t*)wp;               wp += NGI * 2;
  unsigned* bar     = (unsigned*)wp;               wp += 16;
  ushort_t* logits_bf = (ushort_t*)wp;             // +131MB only if ws allows
  size_t need_big = (size_t)(wp - (char*)d_ws) + (size_t)BB * SS * VV * 2 + 1024;
  bool big = ws_size >= need_big;

  // 1) weight / h0 converts to bf16
  k_f32_to_bf16<<<(int)((NWOUT/4 + 255)/256), 256, 0, stream>>>(W_out, wout_bf, (int)(NWOUT/4));
  k_f32_to_bf16<<<(int)((NW3H/4  + 255)/256), 256, 0, stream>>>(W_ih,  wih_bf,  (int)(NW3H/4));
  k_f32_to_bf16<<<(int)((NW3H/4  + 255)/256), 256, 0, stream>>>(W_hh,  whh_bf,  (int)(NW3H/4));
  k_f32_to_bf16<<<(int)((NH0/4   + 255)/256), 256, 0, stream>>>(enc_hid, h0_bf, (int)(NH0/4));

  // 2) x = relu(emb[tok]) bf16, rows r = s*32+b
  k_embed<<<SS*BB, 256, 0, stream>>>(emb, tgt, bosp, x_bf);

  // 3) gi = x @ W_ih^T + b_ih  (bf16 out)
  k_gemm_bt<true><<<dim3(16, 24), 256, 0, stream>>>(x_bf, wih_bf, b_ih, gi_bf, 2048, 3072, 1024, 0);

  // 4) recurrence: single persistent launch, grid barrier per step; also writes hT tail
  hipMemsetAsync(bar, 0, 4, stream);
  k_gru_persist<<<GRU_WGS, 256, 0, stream>>>(h0_bf, enc_hid, whh_bf, gi_bf, b_hh,
                                             hs_bf, out + (size_t)BB * SS * VV, bar);

  // 5) logits + log_softmax
  if (big){
    k_gemm_bt<true><<<dim3(16, 250), 256, 0, stream>>>(hs_bf, wout_bf, b_out, logits_bf,
                                                       2048, VV, 1024, 1);
    k_lsm_bf<<<SS*BB, 256, 0, stream>>>(logits_bf, out);
  } else {
    k_gemm_bt<false><<<dim3(16, 250), 256, 0, stream>>>(hs_bf, wout_bf, b_out, out,
                                                        2048, VV, 1024, 1);
    k_logsoftmax<<<SS*BB, 256, 0, stream>>>(out);
  }
}